// Round 14
// baseline (95.995 us; speedup 1.0000x reference)
//
#include <hip/hip_runtime.h>
#include <hip/hip_bf16.h>

#define B_ROWS 4096
#define D_DIM  512
#define N_ROWS 8192
#define EPS_N  1e-8f
#define INV_T  20.0f
// exp(20*sim) = exp2(acc * FACT); acc = 1024*sim (global fp4 scale 2^-5 on both operands)
#define FACT   0.0281778328298626f             // 20 / ln(2) / 1024
#define CSPLIT 8
#define BM 256                                  // rows per block (= one panel)
#define BN 128                                  // cols per strip (= half panel)
#define COLS_PER_CHUNK (N_ROWS / CSPLIT)        // 1024
#define STRIPS (COLS_PER_CHUNK / BN)            // 8
#define A_BYTES 65536                           // A panel: [16 kg][256 row][16B] fp4
#define B_BYTES 32768                           // B strip: [16 kg][128 col][16B]
#define PANEL_BYTES 65536                       // global: [16 kg][256 row][16B]

typedef __attribute__((ext_vector_type(16))) float floatx16;
typedef __attribute__((ext_vector_type(8)))  int   intx8;
typedef __attribute__((ext_vector_type(4)))  int   intx4;

#define AS1C(p) ((const __attribute__((address_space(1))) void*)(p))
#define AS3(p)  ((__attribute__((address_space(3))) void*)(p))
// widen intx4 -> intx8 with UNDEF high half (fp4 MFMA reads only v[0:3])
#define W8(a) __builtin_shufflevector((a), (a), 0, 1, 2, 3, -1, -1, -1, -1)

// MX scale 1.0 in E8M0 (bias 127); opsel=0 picks byte 0. cbsz=blgp=4 -> fp4 e2m1
#define SC1 0x7F7F7F7F
#define MXMFMA4(A, B, C) \
  __builtin_amdgcn_mfma_scale_f32_32x32x64_f8f6f4((A), (B), (C), 4, 4, 0, SC1, 0, SC1)

// sorted-insert via med3: new_t[i] = median(v, t[i], t[i-1]); all-ILP
__device__ __forceinline__ void insert5(float (&t)[5], float v) {
  float n0 = fmaxf(t[0], v);
  float n1 = __builtin_amdgcn_fmed3f(v, t[1], t[0]);
  float n2 = __builtin_amdgcn_fmed3f(v, t[2], t[1]);
  float n3 = __builtin_amdgcn_fmed3f(v, t[3], t[2]);
  float n4 = __builtin_amdgcn_fmed3f(v, t[4], t[3]);
  t[0] = n0; t[1] = n1; t[2] = n2; t[3] = n3; t[4] = n4;
}

// e2m1 encode (RNE): values {0,.5,1,1.5,2,3,4,6}, sign in bit 3
__device__ __forceinline__ unsigned enc_fp4(float y) {
  float f = fminf(fabsf(y), 6.0f);
  float c1 = rintf(f + f);
  float c2 = rintf(f - 2.0f) + 4.0f;
  float c3 = rintf((f - 4.0f) * 0.5f) + 6.0f;
  float c = (f < 2.0f) ? c1 : ((f < 4.0f) ? c2 : c3);
  return (unsigned)c | ((__float_as_uint(y) >> 31) << 3);
}

// ---- kernel 1: normalize -> fp4 e2m1 (scale 2^-5) in panel/kg layout, dot(f1,f2) ----
__global__ __launch_bounds__(256) void prep_kernel(
    const float* __restrict__ f1, const float* __restrict__ f2,
    unsigned char* __restrict__ fnb4, float* __restrict__ dots)
{
  int row = blockIdx.x;          // 0..4095
  int t = threadIdx.x;
  const float* r1 = f1 + (size_t)row * D_DIM;
  const float* r2 = f2 + (size_t)row * D_DIM;
  float2 a = *(const float2*)(r1 + 2 * t);
  float2 b = *(const float2*)(r2 + 2 * t);
  float s1 = a.x * a.x + a.y * a.y;
  float s2 = b.x * b.x + b.y * b.y;
  float d  = a.x * b.x + a.y * b.y;
  #pragma unroll
  for (int off = 32; off >= 1; off >>= 1) {
    s1 += __shfl_down(s1, off);
    s2 += __shfl_down(s2, off);
    d  += __shfl_down(d, off);
  }
  __shared__ float red[4][3];
  __shared__ float bc[2];
  int wave = t >> 6, lane = t & 63;
  if (lane == 0) { red[wave][0] = s1; red[wave][1] = s2; red[wave][2] = d; }
  __syncthreads();
  if (t == 0) {
    float S1 = red[0][0] + red[1][0] + red[2][0] + red[3][0];
    float S2 = red[0][1] + red[1][1] + red[2][1] + red[3][1];
    float Dd = red[0][2] + red[1][2] + red[2][2] + red[3][2];
    bc[0] = 1.0f / fmaxf(sqrtf(S1), EPS_N);
    bc[1] = 1.0f / fmaxf(sqrtf(S2), EPS_N);
    dots[row] = Dd;
  }
  __syncthreads();
  if (t < 128) {
    int q = t & 63;
    int is2 = t >> 6;
    const float* src = (is2 ? f2 : f1) + (size_t)row * D_DIM + q * 8;
    float sc = bc[is2] * 32.0f;            // normalize then / 2^-5
    float4 v0 = *(const float4*)(src);
    float4 v1 = *(const float4*)(src + 4);
    unsigned p = enc_fp4(v0.x * sc);
    p |= enc_fp4(v0.y * sc) << 4;
    p |= enc_fp4(v0.z * sc) << 8;
    p |= enc_fp4(v0.w * sc) << 12;
    p |= enc_fp4(v1.x * sc) << 16;
    p |= enc_fp4(v1.y * sc) << 20;
    p |= enc_fp4(v1.z * sc) << 24;
    p |= enc_fp4(v1.w * sc) << 28;
    int grow = row + is2 * B_ROWS;
    int panel = grow >> 8, rin = grow & 255;
    int kg = q >> 2;
    *(unsigned*)(fnb4 + (size_t)panel * PANEL_BYTES + kg * 4096 + rin * 16
                 + (q & 3) * 4) = p;
  }
}

// ---- kernel 2: MX fp4 sim; A panel static in LDS, B strip dbuf; acc double-buffer
// pipelines scan(strip s-1) against MFMA(strip s). 1024 thr, 4x4 waves, tile 64x32.
__global__ __launch_bounds__(1024, 4) void sim_kernel(
    const unsigned char* __restrict__ fnb4,
    float* __restrict__ partials)      // [N_ROWS][CSPLIT][6] = sum, top5 (desc)
{
  __shared__ int4 lds4[8192];          // 128 KiB: A 64K + B0 32K + B1 32K
  char* lds = (char*)lds4;

  int bx = blockIdx.x;                 // 0..255
  int xcd = bx & 7, kk = bx >> 3;
  int rt = xcd * 4 + (kk & 3);         // A panel index 0..31
  int chunk = kk >> 2;                 // 0..7
  int rowbase = rt * BM;
  int chunkbase = chunk * COLS_PER_CHUNK;

  int t = threadIdx.x;
  int wave = t >> 6, lane = t & 63;
  int wr = wave >> 2, wc = wave & 3;   // 4x4 wave grid; wave tile 64 rows x 32 cols
  int l31 = lane & 31, lh = lane >> 5;

  int arow16 = (wr * 64 + l31) * 16;   // A frag byte (rb0); rb1 = +512
  int bcol16 = (wc * 32 + l31) * 16;   // B frag byte within kg plane

  const char* gA  = (const char*)fnb4 + (size_t)rt * PANEL_BYTES;
  const char* gB0 = (const char*)fnb4 + (size_t)(chunk * 4) * PANEL_BYTES;

  float sum[2][2];
  float top[2][5];
  floatx16 accA[2], accB[2];
  #pragma unroll
  for (int rb = 0; rb < 2; ++rb) {
    sum[rb][0] = sum[rb][1] = 0.f;
    #pragma unroll
    for (int k = 0; k < 5; ++k) top[rb][k] = -3.0e38f;
    #pragma unroll
    for (int e = 0; e < 16; ++e) { accA[rb][e] = 0.0f; accB[rb][e] = 0.0f; }
  }

  // prologue: stage A panel (4KB/wave) + B strip 0 (2KB/wave)
  {
    const char* sa = gA + wave * 4096 + lane * 16;
    char* da = lds + wave * 4096;
    #pragma unroll
    for (int q = 0; q < 4; ++q)
      __builtin_amdgcn_global_load_lds(AS1C(sa + q * 1024), AS3(da + q * 1024), 16, 0, 0);
    const char* sb = gB0 + wave * 4096 + lane * 16;   // strip 0: half 0 of panel chunk*4
    char* db = lds + A_BYTES + wave * 2048;
    #pragma unroll
    for (int q = 0; q < 2; ++q)
      __builtin_amdgcn_global_load_lds(AS1C(sb + q * 1024), AS3(db + q * 1024), 16, 0, 0);
  }
  __syncthreads();

  // scan strip sp from acc (raw acc domain), with diag poison; resets acc
  auto scanP = [&](floatx16 (&acc)[2], int sp) {
    int d = (chunkbase + sp * BN + wc * 32) - (rowbase + wr * 64);
    if ((d == 0 || d == 32) && lh == ((l31 >> 2) & 1)) {
      int rd = (l31 & 3) | (((l31 >> 3) & 3) << 2);
      acc[d >> 5][rd] = -1e30f;        // excluded from sum (exp->0) and from top
    }
    #pragma unroll
    for (int rb = 0; rb < 2; ++rb)
      #pragma unroll
      for (int r = 0; r < 16; ++r) {
        float v = acc[rb][r];
        sum[rb][r & 1] += exp2f(v * FACT);
        insert5(top[rb], v);
        acc[rb][r] = 0.0f;
      }
  };

  // one strip: MFMA strip s into accC while scanning strip s-1 from accP
  auto iter = [&](int s, floatx16 (&accC)[2], floatx16 (&accP)[2], bool doScan) {
    const char* Bs = lds + A_BYTES + (s & 1) * B_BYTES;
    if (s + 1 < STRIPS) {
      const char* sb = gB0 + (size_t)((s + 1) >> 1) * PANEL_BYTES
                     + wave * 4096 + ((s + 1) & 1) * 2048 + lane * 16;
      char* db = lds + A_BYTES + ((s + 1) & 1) * B_BYTES + wave * 2048;
      #pragma unroll
      for (int q = 0; q < 2; ++q)
        __builtin_amdgcn_global_load_lds(AS1C(sb + q * 1024), AS3(db + q * 1024), 16, 0, 0);
    }
    if (doScan) scanP(accP, s - 1);
    #pragma unroll
    for (int kq = 0; kq < 8; ++kq) {
      int kg = kq * 2 + lh;            // kgroup 0..15
      intx4 rf0 = *(const intx4*)(lds + kg * 4096 + arow16);
      intx4 rf1 = *(const intx4*)(lds + kg * 4096 + arow16 + 512);
      intx4 cf  = *(const intx4*)(Bs  + kg * 2048 + bcol16);
      accC[0] = MXMFMA4(W8(cf), W8(rf0), accC[0]);
      accC[1] = MXMFMA4(W8(cf), W8(rf1), accC[1]);
    }
    __syncthreads();                   // reads of Bs done + next strip resident
  };

  iter(0, accA, accB, false);
  #pragma unroll 1
  for (int ss = 0; ss < 3; ++ss) {
    iter(2 * ss + 1, accB, accA, true);
    iter(2 * ss + 2, accA, accB, true);
  }
  iter(7, accB, accA, true);           // scans strip 6
  scanP(accB, 7);                      // final strip

  // fold sum chains; merge lane l <-> l+32 (same rows, disjoint col subsets)
  float rsum[2];
  #pragma unroll
  for (int rb = 0; rb < 2; ++rb) {
    rsum[rb] = sum[rb][0] + sum[rb][1];
    rsum[rb] += __shfl_xor(rsum[rb], 32);
    float pt[5];
    #pragma unroll
    for (int k = 0; k < 5; ++k) pt[k] = __shfl_xor(top[rb][k], 32);
    #pragma unroll
    for (int k = 0; k < 5; ++k) insert5(top[rb], pt[k]);
  }

  // cross-wave merge: 4 wc-waves hold disjoint col ranges of the same rows
  float* mbuf = (float*)lds;           // [16 waves][2 rb][32 lanes][6] = 24 KiB
  if (lane < 32) {
    #pragma unroll
    for (int rb = 0; rb < 2; ++rb) {
      float* dst = mbuf + (size_t)(((wave * 2 + rb) * 32) + lane) * 6;
      dst[0] = rsum[rb];
      #pragma unroll
      for (int k = 0; k < 5; ++k) dst[1 + k] = top[rb][k];
    }
  }
  __syncthreads();
  if (t < 256) {                       // thread t owns block-row t
    int wr2 = t >> 6, rb2 = (t >> 5) & 1, r31 = t & 31;
    float s = 0.0f;
    float a5[5] = {-3.0e38f, -3.0e38f, -3.0e38f, -3.0e38f, -3.0e38f};
    #pragma unroll
    for (int wc2 = 0; wc2 < 4; ++wc2) {
      int w = wr2 * 4 + wc2;
      const float* src = mbuf + (size_t)(((w * 2 + rb2) * 32) + r31) * 6;
      s += src[0];
      #pragma unroll
      for (int k = 0; k < 5; ++k) insert5(a5, src[1 + k]);
    }
    int grow = rowbase + t;
    float* dst = partials + ((size_t)grow * CSPLIT + chunk) * 6;
    dst[0] = s;
    #pragma unroll
    for (int k = 0; k < 5; ++k) dst[1 + k] = exp2f(a5[k] * FACT);
  }
}

// -------------------- kernel 3a: per-row loss, 32-block partial sums ----------
__global__ __launch_bounds__(256) void finalize1_kernel(
    const float* __restrict__ partials, const float* __restrict__ dots,
    float* __restrict__ bpart)
{
  int row = blockIdx.x * 256 + threadIdx.x;    // 32*256 = 8192
  const float* p = partials + (size_t)row * (CSPLIT * 6);
  float s = 0.0f;
  float a5[5] = {0.f, 0.f, 0.f, 0.f, 0.f};
  #pragma unroll
  for (int c = 0; c < CSPLIT; ++c) {
    s += p[c * 6];
    #pragma unroll
    for (int k = 0; k < 5; ++k) insert5(a5, p[c * 6 + 1 + k]);
  }
  float ng = s - (a5[0] + a5[1] + a5[2] + a5[3] + a5[4]);
  float dv = dots[row & (B_ROWS - 1)];
  float acc = __logf(ng + __expf(dv * INV_T)) - dv * INV_T;

  #pragma unroll
  for (int off = 32; off >= 1; off >>= 1) acc += __shfl_down(acc, off);
  __shared__ float red[4];
  int wave = threadIdx.x >> 6, lane = threadIdx.x & 63;
  if (lane == 0) red[wave] = acc;
  __syncthreads();
  if (threadIdx.x == 0)
    bpart[blockIdx.x] = red[0] + red[1] + red[2] + red[3];
}

// -------------------- kernel 3b: final reduce --------------------
__global__ __launch_bounds__(64) void finalize2_kernel(
    const float* __restrict__ bpart, float* __restrict__ out)
{
  int t = threadIdx.x;
  float v = (t < 32) ? bpart[t] : 0.0f;
  #pragma unroll
  for (int off = 32; off >= 1; off >>= 1) v += __shfl_down(v, off);
  if (t == 0) out[0] = v / (float)N_ROWS;
}

extern "C" void kernel_launch(void* const* d_in, const int* in_sizes, int n_in,
                              void* d_out, int out_size, void* d_ws, size_t ws_size,
                              hipStream_t stream) {
  const float* f1 = (const float*)d_in[0];
  const float* f2 = (const float*)d_in[1];
  float* out = (float*)d_out;
  char* ws = (char*)d_ws;

  unsigned char* fnb4 = (unsigned char*)ws;                           // 2 MiB
  float* dots = (float*)(ws + (size_t)4 * 1024 * 1024);               // 16 KiB
  float* partials = (float*)(ws + (size_t)4 * 1024 * 1024 + 65536);   // 1.5 MiB
  float* bpart = (float*)(ws + (size_t)8 * 1024 * 1024);              // 128 B

  prep_kernel<<<B_ROWS, 256, 0, stream>>>(f1, f2, fnb4, dots);
  sim_kernel<<<(N_ROWS / BM) * CSPLIT, 1024, 0, stream>>>(fnb4, partials);
  finalize1_kernel<<<32, 256, 0, stream>>>(partials, dots, bpart);
  finalize2_kernel<<<1, 64, 0, stream>>>(bpart, out);
}

// Round 15
// 95.505 us; speedup vs baseline: 1.0051x; 1.0051x over previous
//
#include <hip/hip_runtime.h>
#include <hip/hip_bf16.h>

#define B_ROWS 4096
#define D_DIM  512
#define N_ROWS 8192
#define EPS_N  1e-8f
#define INV_T  20.0f
// exp(20*sim) = exp2(acc * FACT); acc = 1024*sim (global fp4 scale 2^-5 on both operands)
#define FACT   0.0281778328298626f             // 20 / ln(2) / 1024
#define CSPLIT 8
#define BM 256                                  // rows per block (= one panel)
#define BN 128                                  // cols per strip (= half panel)
#define COLS_PER_CHUNK (N_ROWS / CSPLIT)        // 1024
#define STRIPS (COLS_PER_CHUNK / BN)            // 8
#define A_BYTES 65536                           // A panel: [16 kg][256 row][16B] fp4
#define B_BYTES 32768                           // B strip: [16 kg][128 col][16B]
#define PANEL_BYTES 65536                       // global: [16 kg][256 row][16B]

typedef __attribute__((ext_vector_type(16))) float floatx16;
typedef __attribute__((ext_vector_type(8)))  int   intx8;
typedef __attribute__((ext_vector_type(4)))  int   intx4;

#define AS1C(p) ((const __attribute__((address_space(1))) void*)(p))
#define AS3(p)  ((__attribute__((address_space(3))) void*)(p))
// widen intx4 -> intx8 with UNDEF high half (fp4 MFMA reads only v[0:3])
#define W8(a) __builtin_shufflevector((a), (a), 0, 1, 2, 3, -1, -1, -1, -1)

// MX scale 1.0 in E8M0 (bias 127); opsel=0 picks byte 0. cbsz=blgp=4 -> fp4 e2m1
#define SC1 0x7F7F7F7F
#define MXMFMA4(A, B, C) \
  __builtin_amdgcn_mfma_scale_f32_32x32x64_f8f6f4((A), (B), (C), 4, 4, 0, SC1, 0, SC1)

// sorted-insert via med3: new_t[i] = median(v, t[i], t[i-1]); all-ILP
__device__ __forceinline__ void insert5(float (&t)[5], float v) {
  float n0 = fmaxf(t[0], v);
  float n1 = __builtin_amdgcn_fmed3f(v, t[1], t[0]);
  float n2 = __builtin_amdgcn_fmed3f(v, t[2], t[1]);
  float n3 = __builtin_amdgcn_fmed3f(v, t[3], t[2]);
  float n4 = __builtin_amdgcn_fmed3f(v, t[4], t[3]);
  t[0] = n0; t[1] = n1; t[2] = n2; t[3] = n3; t[4] = n4;
}

// e2m1 encode (RNE): values {0,.5,1,1.5,2,3,4,6}, sign in bit 3
__device__ __forceinline__ unsigned enc_fp4(float y) {
  float f = fminf(fabsf(y), 6.0f);
  float c1 = rintf(f + f);
  float c2 = rintf(f - 2.0f) + 4.0f;
  float c3 = rintf((f - 4.0f) * 0.5f) + 6.0f;
  float c = (f < 2.0f) ? c1 : ((f < 4.0f) ? c2 : c3);
  return (unsigned)c | ((__float_as_uint(y) >> 31) << 3);
}

// ---- kernel 1: normalize -> fp4 e2m1 (scale 2^-5) in panel/kg layout, dot(f1,f2) ----
__global__ __launch_bounds__(256) void prep_kernel(
    const float* __restrict__ f1, const float* __restrict__ f2,
    unsigned char* __restrict__ fnb4, float* __restrict__ dots)
{
  int row = blockIdx.x;          // 0..4095
  int t = threadIdx.x;
  const float* r1 = f1 + (size_t)row * D_DIM;
  const float* r2 = f2 + (size_t)row * D_DIM;
  float2 a = *(const float2*)(r1 + 2 * t);
  float2 b = *(const float2*)(r2 + 2 * t);
  float s1 = a.x * a.x + a.y * a.y;
  float s2 = b.x * b.x + b.y * b.y;
  float d  = a.x * b.x + a.y * b.y;
  #pragma unroll
  for (int off = 32; off >= 1; off >>= 1) {
    s1 += __shfl_down(s1, off);
    s2 += __shfl_down(s2, off);
    d  += __shfl_down(d, off);
  }
  __shared__ float red[4][3];
  __shared__ float bc[2];
  int wave = t >> 6, lane = t & 63;
  if (lane == 0) { red[wave][0] = s1; red[wave][1] = s2; red[wave][2] = d; }
  __syncthreads();
  if (t == 0) {
    float S1 = red[0][0] + red[1][0] + red[2][0] + red[3][0];
    float S2 = red[0][1] + red[1][1] + red[2][1] + red[3][1];
    float Dd = red[0][2] + red[1][2] + red[2][2] + red[3][2];
    bc[0] = 1.0f / fmaxf(sqrtf(S1), EPS_N);
    bc[1] = 1.0f / fmaxf(sqrtf(S2), EPS_N);
    dots[row] = Dd;
  }
  __syncthreads();
  if (t < 128) {
    int q = t & 63;
    int is2 = t >> 6;
    const float* src = (is2 ? f2 : f1) + (size_t)row * D_DIM + q * 8;
    float sc = bc[is2] * 32.0f;            // normalize then / 2^-5
    float4 v0 = *(const float4*)(src);
    float4 v1 = *(const float4*)(src + 4);
    unsigned p = enc_fp4(v0.x * sc);
    p |= enc_fp4(v0.y * sc) << 4;
    p |= enc_fp4(v0.z * sc) << 8;
    p |= enc_fp4(v0.w * sc) << 12;
    p |= enc_fp4(v1.x * sc) << 16;
    p |= enc_fp4(v1.y * sc) << 20;
    p |= enc_fp4(v1.z * sc) << 24;
    p |= enc_fp4(v1.w * sc) << 28;
    int grow = row + is2 * B_ROWS;
    int panel = grow >> 8, rin = grow & 255;
    int kg = q >> 2;
    *(unsigned*)(fnb4 + (size_t)panel * PANEL_BYTES + kg * 4096 + rin * 16
                 + (q & 3) * 4) = p;
  }
}

// ---- kernel 2: MX fp4 sim; A panel static in LDS, B strip dbuf; acc double-buffer
// pipelines scan(strip s-1) against MFMA(strip s). 1024 thr, 4x4 waves, tile 64x32.
__global__ __launch_bounds__(1024, 4) void sim_kernel(
    const unsigned char* __restrict__ fnb4,
    float* __restrict__ partials)      // [N_ROWS][CSPLIT][6] = sum, top5 (desc)
{
  __shared__ int4 lds4[8192];          // 128 KiB: A 64K + B0 32K + B1 32K
  char* lds = (char*)lds4;

  int bx = blockIdx.x;                 // 0..255
  int xcd = bx & 7, kk = bx >> 3;
  int rt = xcd * 4 + (kk & 3);         // A panel index 0..31
  int chunk = kk >> 2;                 // 0..7
  int rowbase = rt * BM;
  int chunkbase = chunk * COLS_PER_CHUNK;

  int t = threadIdx.x;
  int wave = t >> 6, lane = t & 63;
  int wr = wave >> 2, wc = wave & 3;   // 4x4 wave grid; wave tile 64 rows x 32 cols
  int l31 = lane & 31, lh = lane >> 5;

  int arow16 = (wr * 64 + l31) * 16;   // A frag byte (rb0); rb1 = +512
  int bcol16 = (wc * 32 + l31) * 16;   // B frag byte within kg plane

  const char* gA  = (const char*)fnb4 + (size_t)rt * PANEL_BYTES;
  const char* gB0 = (const char*)fnb4 + (size_t)(chunk * 4) * PANEL_BYTES;

  float sum[2][2];
  float top[2][5];
  floatx16 accA[2], accB[2];
  #pragma unroll
  for (int rb = 0; rb < 2; ++rb) {
    sum[rb][0] = sum[rb][1] = 0.f;
    #pragma unroll
    for (int k = 0; k < 5; ++k) top[rb][k] = -3.0e38f;
    #pragma unroll
    for (int e = 0; e < 16; ++e) { accA[rb][e] = 0.0f; accB[rb][e] = 0.0f; }
  }

  // prologue: stage A panel (4KB/wave) + B strip 0 (2KB/wave)
  {
    const char* sa = gA + wave * 4096 + lane * 16;
    char* da = lds + wave * 4096;
    #pragma unroll
    for (int q = 0; q < 4; ++q)
      __builtin_amdgcn_global_load_lds(AS1C(sa + q * 1024), AS3(da + q * 1024), 16, 0, 0);
    const char* sb = gB0 + wave * 4096 + lane * 16;   // strip 0: half 0 of panel chunk*4
    char* db = lds + A_BYTES + wave * 2048;
    #pragma unroll
    for (int q = 0; q < 2; ++q)
      __builtin_amdgcn_global_load_lds(AS1C(sb + q * 1024), AS3(db + q * 1024), 16, 0, 0);
  }
  __syncthreads();

  // scan strip sp from acc (raw acc domain), with diag poison; resets acc
  auto scanP = [&](floatx16 (&acc)[2], int sp) {
    int d = (chunkbase + sp * BN + wc * 32) - (rowbase + wr * 64);
    if ((d == 0 || d == 32) && lh == ((l31 >> 2) & 1)) {
      int rd = (l31 & 3) | (((l31 >> 3) & 3) << 2);
      acc[d >> 5][rd] = -1e30f;        // excluded from sum (exp->0) and from top
    }
    #pragma unroll
    for (int rb = 0; rb < 2; ++rb)
      #pragma unroll
      for (int r = 0; r < 16; ++r) {
        float v = acc[rb][r];
        sum[rb][r & 1] += exp2f(v * FACT);
        insert5(top[rb], v);
        acc[rb][r] = 0.0f;
      }
  };

  // one strip: MFMA strip s into accC while scanning strip s-1 from accP
  auto iter = [&](int s, floatx16 (&accC)[2], floatx16 (&accP)[2], bool doScan) {
    const char* Bs = lds + A_BYTES + (s & 1) * B_BYTES;
    if (s + 1 < STRIPS) {
      const char* sb = gB0 + (size_t)((s + 1) >> 1) * PANEL_BYTES
                     + wave * 4096 + ((s + 1) & 1) * 2048 + lane * 16;
      char* db = lds + A_BYTES + ((s + 1) & 1) * B_BYTES + wave * 2048;
      #pragma unroll
      for (int q = 0; q < 2; ++q)
        __builtin_amdgcn_global_load_lds(AS1C(sb + q * 1024), AS3(db + q * 1024), 16, 0, 0);
    }
    if (doScan) scanP(accP, s - 1);
    #pragma unroll
    for (int kq = 0; kq < 8; ++kq) {
      int kg = kq * 2 + lh;            // kgroup 0..15
      intx4 rf0 = *(const intx4*)(lds + kg * 4096 + arow16);
      intx4 rf1 = *(const intx4*)(lds + kg * 4096 + arow16 + 512);
      intx4 cf  = *(const intx4*)(Bs  + kg * 2048 + bcol16);
      accC[0] = MXMFMA4(W8(cf), W8(rf0), accC[0]);
      accC[1] = MXMFMA4(W8(cf), W8(rf1), accC[1]);
    }
    __syncthreads();                   // reads of Bs done + next strip resident
  };

  iter(0, accA, accB, false);
  #pragma unroll 1
  for (int ss = 0; ss < 3; ++ss) {
    iter(2 * ss + 1, accB, accA, true);
    iter(2 * ss + 2, accA, accB, true);
  }
  iter(7, accB, accA, true);           // scans strip 6
  scanP(accB, 7);                      // final strip

  // fold sum chains; merge lane l <-> l+32 (same rows, disjoint col subsets)
  float rsum[2];
  #pragma unroll
  for (int rb = 0; rb < 2; ++rb) {
    rsum[rb] = sum[rb][0] + sum[rb][1];
    rsum[rb] += __shfl_xor(rsum[rb], 32);
    float pt[5];
    #pragma unroll
    for (int k = 0; k < 5; ++k) pt[k] = __shfl_xor(top[rb][k], 32);
    #pragma unroll
    for (int k = 0; k < 5; ++k) insert5(top[rb], pt[k]);
  }

  // cross-wave merge: 4 wc-waves hold disjoint col ranges of the same rows
  float* mbuf = (float*)lds;           // [16 waves][2 rb][32 lanes][6] = 24 KiB
  if (lane < 32) {
    #pragma unroll
    for (int rb = 0; rb < 2; ++rb) {
      float* dst = mbuf + (size_t)(((wave * 2 + rb) * 32) + lane) * 6;
      dst[0] = rsum[rb];
      #pragma unroll
      for (int k = 0; k < 5; ++k) dst[1 + k] = top[rb][k];
    }
  }
  __syncthreads();
  if (t < 256) {                       // thread t owns block-row t
    int wr2 = t >> 6, rb2 = (t >> 5) & 1, r31 = t & 31;
    float s = 0.0f;
    float a5[5] = {-3.0e38f, -3.0e38f, -3.0e38f, -3.0e38f, -3.0e38f};
    #pragma unroll
    for (int wc2 = 0; wc2 < 4; ++wc2) {
      int w = wr2 * 4 + wc2;
      const float* src = mbuf + (size_t)(((w * 2 + rb2) * 32) + r31) * 6;
      s += src[0];
      #pragma unroll
      for (int k = 0; k < 5; ++k) insert5(a5, src[1 + k]);
    }
    int grow = rowbase + t;
    float* dst = partials + ((size_t)grow * CSPLIT + chunk) * 6;
    dst[0] = s;
    #pragma unroll
    for (int k = 0; k < 5; ++k) dst[1 + k] = exp2f(a5[k] * FACT);
  }
}

// -------------------- kernel 3a: per-row loss, 32-block partial sums ----------
__global__ __launch_bounds__(256) void finalize1_kernel(
    const float* __restrict__ partials, const float* __restrict__ dots,
    float* __restrict__ bpart)
{
  int row = blockIdx.x * 256 + threadIdx.x;    // 32*256 = 8192
  const float* p = partials + (size_t)row * (CSPLIT * 6);
  float s = 0.0f;
  float a5[5] = {0.f, 0.f, 0.f, 0.f, 0.f};
  #pragma unroll
  for (int c = 0; c < CSPLIT; ++c) {
    s += p[c * 6];
    #pragma unroll
    for (int k = 0; k < 5; ++k) insert5(a5, p[c * 6 + 1 + k]);
  }
  float ng = s - (a5[0] + a5[1] + a5[2] + a5[3] + a5[4]);
  float dv = dots[row & (B_ROWS - 1)];
  float acc = __logf(ng + __expf(dv * INV_T)) - dv * INV_T;

  #pragma unroll
  for (int off = 32; off >= 1; off >>= 1) acc += __shfl_down(acc, off);
  __shared__ float red[4];
  int wave = threadIdx.x >> 6, lane = threadIdx.x & 63;
  if (lane == 0) red[wave] = acc;
  __syncthreads();
  if (threadIdx.x == 0)
    bpart[blockIdx.x] = red[0] + red[1] + red[2] + red[3];
}

// -------------------- kernel 3b: final reduce --------------------
__global__ __launch_bounds__(64) void finalize2_kernel(
    const float* __restrict__ bpart, float* __restrict__ out)
{
  int t = threadIdx.x;
  float v = (t < 32) ? bpart[t] : 0.0f;
  #pragma unroll
  for (int off = 32; off >= 1; off >>= 1) v += __shfl_down(v, off);
  if (t == 0) out[0] = v / (float)N_ROWS;
}

extern "C" void kernel_launch(void* const* d_in, const int* in_sizes, int n_in,
                              void* d_out, int out_size, void* d_ws, size_t ws_size,
                              hipStream_t stream) {
  const float* f1 = (const float*)d_in[0];
  const float* f2 = (const float*)d_in[1];
  float* out = (float*)d_out;
  char* ws = (char*)d_ws;

  unsigned char* fnb4 = (unsigned char*)ws;                           // 2 MiB
  float* dots = (float*)(ws + (size_t)4 * 1024 * 1024);               // 16 KiB
  float* partials = (float*)(ws + (size_t)4 * 1024 * 1024 + 65536);   // 1.5 MiB
  float* bpart = (float*)(ws + (size_t)8 * 1024 * 1024);              // 128 B

  prep_kernel<<<B_ROWS, 256, 0, stream>>>(f1, f2, fnb4, dots);
  sim_kernel<<<(N_ROWS / BM) * CSPLIT, 1024, 0, stream>>>(fnb4, partials);
  finalize1_kernel<<<32, 256, 0, stream>>>(partials, dots, bpart);
  finalize2_kernel<<<1, 64, 0, stream>>>(bpart, out);
}